// Round 8
// baseline (169.990 us; speedup 1.0000x reference)
//
#include <hip/hip_runtime.h>
#include <math.h>

// Problem shape (fixed by harness reference)
#define B_SZ 32
#define NM   2048     // N == M == 2048
#define D_SZ 32

typedef __attribute__((ext_vector_type(8))) _Float16 h8;   // MFMA A/B frag: 8 f16 = 4 VGPRs
typedef __attribute__((ext_vector_type(4))) float f4;      // MFMA C/D frag

// ---------------------------------------------------------------------------
// Pack X (and Y) into MFMA-fragment-ready f16 layout + fused squared norms
// (verified: absmax 0.0 in rounds 2-7). Tile t = 16 consecutive rows of
// flattened [B*NM]; lane l holds row t*16+(l&15), k = {4g+j} U {16+4g+j}.
// ---------------------------------------------------------------------------
__global__ __launch_bounds__(256)
void pack_kernel(const float* __restrict__ srcX, const float* __restrict__ srcY,
                 h8* __restrict__ dstX, h8* __restrict__ dstY,
                 float* __restrict__ nrmX, float* __restrict__ nrmY)
{
    const int gid = blockIdx.x * 256 + threadIdx.x;   // one thread per (tile,lane)
    const float* src = blockIdx.y ? srcY : srcX;
    h8*          dst = blockIdx.y ? dstY : dstX;
    float*       nrm = blockIdx.y ? nrmY : nrmX;

    const int l   = gid & 63;
    const int t   = gid >> 6;
    const int row = t * 16 + (l & 15);
    const int k0  = (l >> 4) * 4;

    const float* p = src + (size_t)row * D_SZ;
    f4 v0 = *(const f4*)(p + k0);        // k = k0..k0+3
    f4 v1 = *(const f4*)(p + 16 + k0);   // k = 16+k0..16+k0+3

    h8 h;
    h[0] = (_Float16)v0[0]; h[1] = (_Float16)v0[1];
    h[2] = (_Float16)v0[2]; h[3] = (_Float16)v0[3];
    h[4] = (_Float16)v1[0]; h[5] = (_Float16)v1[1];
    h[6] = (_Float16)v1[2]; h[7] = (_Float16)v1[3];
    dst[gid] = h;

    float s = 0.f;
#pragma unroll
    for (int j = 0; j < 4; ++j) {
        s = fmaf(v0[j], v0[j], s);
        s = fmaf(v1[j], v1[j], s);
    }
    s += __shfl_xor(s, 16);
    s += __shfl_xor(s, 32);
    if (l < 16) nrm[row] = s;   // exact fp32 norms
}

// ---------------------------------------------------------------------------
// One directional pass. dir=0: rows=X, cols=Y (X_inf). dir=1: roles swapped.
// 1D grid, XCD-swizzled (verified round 5: FETCH 37->12.6 MB): logical =
// (phys%8)*(nwg/8)+phys/8 groups the 8 row-blocks of one (dir,half,b) onto
// one XCD so its working set fits the 4MB private L2.
// Block = 4 waves, each owning 64 rows (4 A-frags); ALL waves sweep the SAME
// B-tile stream; 4-deep register prefetch (round 6, verified 58.6->36.6).
// Round 8: nh=4 (tph=32) -> 2048 blocks = 8 blocks/CU, __launch_bounds__
// (256,8) — compiler already sits at 64 VGPR, so this doubles resident waves
// for latency hiding at zero spill cost.
// MFMA C-operand seeded with -0.5*qnorm[col]:
//     min_j d2[i,j] = pnorm[i] - 2 * max_j (dot[i,j] - 0.5*qnorm[j])
// End: shfl-max over 16 col-lanes, lc==0 lanes store rows directly.
// C/D layout (m89-verified): col=lane&15, row=(lane>>4)*4+reg.
// ---------------------------------------------------------------------------
#define PASS_BODY(BF, CV)                                                     \
    {                                                                         \
        const float ch_ = -0.5f * (CV);                                       \
        const f4 cs_ = {ch_, ch_, ch_, ch_};                                  \
        f4 q0 = __builtin_amdgcn_mfma_f32_16x16x32_f16(a0, (BF), cs_, 0,0,0); \
        f4 q1 = __builtin_amdgcn_mfma_f32_16x16x32_f16(a1, (BF), cs_, 0,0,0); \
        f4 q2 = __builtin_amdgcn_mfma_f32_16x16x32_f16(a2, (BF), cs_, 0,0,0); \
        f4 q3 = __builtin_amdgcn_mfma_f32_16x16x32_f16(a3, (BF), cs_, 0,0,0); \
        _Pragma("unroll")                                                     \
        for (int r = 0; r < 4; ++r) {                                         \
            mx0[r] = fmaxf(mx0[r], q0[r]);                                    \
            mx1[r] = fmaxf(mx1[r], q1[r]);                                    \
            mx2[r] = fmaxf(mx2[r], q2[r]);                                    \
            mx3[r] = fmaxf(mx3[r], q3[r]);                                    \
        }                                                                     \
    }

__global__ __launch_bounds__(256, 8)
void chamfer_pass(const h8* __restrict__ Xpk, const h8* __restrict__ Ypk,
                  const float* __restrict__ x2g, const float* __restrict__ y2g,
                  float* __restrict__ mp, int nh, int tph /* = 128/nh */)
{
    // XCD swizzle (nwg = 512/1024/2048, all %8 == 0 -> bijective)
    const int nwg  = gridDim.x;
    const int phys = blockIdx.x;
    const int lg   = (phys & 7) * (nwg >> 3) + (phys >> 3);
    const int xb   = lg & 7;            // 8 row-blocks of 256
    const int rest = lg >> 3;
    const int b    = rest & 31;
    const int z    = rest >> 5;         // 0 .. 2*nh-1
    const int dir  = z / nh;
    const int half = z % nh;

    const int tid = threadIdx.x;
    const int w   = tid >> 6;
    const int l   = tid & 63;
    const int lc  = l & 15;
    const int g   = l >> 4;

    const h8* Ppk = dir ? Ypk : Xpk;
    const h8* Qpk = dir ? Xpk : Ypk;
    const float* qn = dir ? x2g : y2g;

    const int row0 = xb * 256 + w * 64;                   // within batch
    const size_t pt0 = ((size_t)b * NM + row0) >> 4;      // global 16-row tile
    const h8* pa = Ppk + pt0 * 64 + l;
    h8 a0 = pa[0], a1 = pa[64], a2 = pa[128], a3 = pa[192];

    const int mt0 = half * tph;
    const h8*    qb  = Qpk + ((size_t)b * (NM / 16) + mt0) * 64 + l;
    const float* qnb = qn + (size_t)b * NM + mt0 * 16 + lc;

    const float NEGINF = -3.0e38f;
    f4 mx0 = {NEGINF, NEGINF, NEGINF, NEGINF};
    f4 mx1 = mx0, mx2 = mx0, mx3 = mx0;

    // 4-deep register prefetch pipeline (tph is a multiple of 4)
    h8 b0 = qb[0], b1 = qb[64], b2 = qb[128], b3 = qb[192];
    float c0 = qnb[0], c1 = qnb[16], c2 = qnb[32], c3 = qnb[48];

    for (int t = 0; t < tph - 4; t += 4) {
        qb += 4 * 64; qnb += 4 * 16;
        h8 n0 = qb[0], n1 = qb[64], n2 = qb[128], n3 = qb[192];
        float d0 = qnb[0], d1 = qnb[16], d2 = qnb[32], d3 = qnb[48];
        PASS_BODY(b0, c0);
        PASS_BODY(b1, c1);
        PASS_BODY(b2, c2);
        PASS_BODY(b3, c3);
        b0 = n0; b1 = n1; b2 = n2; b3 = n3;
        c0 = d0; c1 = d1; c2 = d2; c3 = d3;
    }
    PASS_BODY(b0, c0);       // tail batch
    PASS_BODY(b1, c1);
    PASS_BODY(b2, c2);
    PASS_BODY(b3, c3);

    // reduce max across the 16 column-lanes
#pragma unroll
    for (int m = 1; m <= 8; m <<= 1) {
#pragma unroll
        for (int r = 0; r < 4; ++r) {
            mx0[r] = fmaxf(mx0[r], __shfl_xor(mx0[r], m));
            mx1[r] = fmaxf(mx1[r], __shfl_xor(mx1[r], m));
            mx2[r] = fmaxf(mx2[r], __shfl_xor(mx2[r], m));
            mx3[r] = fmaxf(mx3[r], __shfl_xor(mx3[r], m));
        }
    }
    if (lc == 0) {   // 4 lanes per wave; rows row0 + i*16 + g*4 .. +3
        float* out = mp + ((size_t)(dir * nh + half) * B_SZ + b) * NM
                        + row0 + (g << 2);
        *(f4*)(out)      = mx0;
        *(f4*)(out + 16) = mx1;
        *(f4*)(out + 32) = mx2;
        *(f4*)(out + 48) = mx3;
    }
}

// ---------------------------------------------------------------------------
// Finalize: d2 = nrm - 2*max(all nh halves), clamp, sqrt, deterministic sum.
// Exactly 32768 f4 elements -> grid 128 x 256, one f4 per thread.
// ---------------------------------------------------------------------------
__global__ __launch_bounds__(256)
void finalize1(const float* __restrict__ mp, const float* __restrict__ nrm,
               float* __restrict__ partials, int nh)
{
    const int i   = blockIdx.x * 256 + threadIdx.x;   // f4 index in [0, 32768)
    const int dir = i >> 14;
    const int r4  = i & 16383;
    const f4* n4 = (const f4*)(nrm + dir * 65536);
    const f4* mb = (const f4*)mp + (size_t)dir * nh * 16384;
    f4 pm = mb[r4];
    for (int h = 1; h < nh; ++h) {
        f4 v = mb[(size_t)h * 16384 + r4];
#pragma unroll
        for (int r = 0; r < 4; ++r) pm[r] = fmaxf(pm[r], v[r]);
    }
    f4 nv = n4[r4];
    float s = 0.f;
#pragma unroll
    for (int r = 0; r < 4; ++r) {
        float d2 = fmaf(-2.f, pm[r], nv[r]);
        s += sqrtf(fmaxf(d2, 0.f));
    }
    __shared__ float wsum[4];
#pragma unroll
    for (int o = 32; o > 0; o >>= 1) s += __shfl_down(s, o, 64);
    if ((threadIdx.x & 63) == 0) wsum[threadIdx.x >> 6] = s;
    __syncthreads();
    if (threadIdx.x == 0)
        partials[blockIdx.x] = wsum[0] + wsum[1] + wsum[2] + wsum[3];
}

__global__ __launch_bounds__(64)
void finalize2(const float* __restrict__ partials, float* __restrict__ out, float scale)
{
    float s = partials[threadIdx.x] + partials[threadIdx.x + 64];
#pragma unroll
    for (int o = 32; o > 0; o >>= 1) s += __shfl_down(s, o, 64);
    if (threadIdx.x == 0) out[0] = s * scale;
}

extern "C" void kernel_launch(void* const* d_in, const int* in_sizes, int n_in,
                              void* d_out, int out_size, void* d_ws, size_t ws_size,
                              hipStream_t stream) {
    const float* X = (const float*)d_in[0];
    const float* Y = (const float*)d_in[1];

    // ws: mp nh*131072 f + partials 128 f + nrm 131072 f + packed 8.39 MB
    // nh=4 -> ~11.0 MB. Fallbacks keep correctness if ws is tight.
    const int nh  = (ws_size >= 12000000u) ? 4
                  : (ws_size >= 10100000u) ? 2 : 1;
    const int tph = 128 / nh;

    float* ws       = (float*)d_ws;
    float* mp       = ws;                              // nh*2*32*2048 floats
    float* partials = mp + (size_t)nh * 131072;        // 128 floats
    float* nrm      = partials + 128;                  // 131072 floats (x2 then y2)
    h8*    Xpk      = (h8*)(nrm + 131072);             // 262144 h8 (4.19 MB)
    h8*    Ypk      = Xpk + 262144;                    // 262144 h8 (4.19 MB)

    dim3 pgrid(1024, 2);
    pack_kernel<<<pgrid, 256, 0, stream>>>(X, Y, Xpk, Ypk, nrm, nrm + 65536);

    // 1D grid: 8 row-blocks x 32 batches x (2*nh) passes, XCD-swizzled inside
    chamfer_pass<<<8 * B_SZ * 2 * nh, 256, 0, stream>>>(Xpk, Ypk, nrm, nrm + 65536,
                                                        mp, nh, tph);

    finalize1<<<128, 256, 0, stream>>>(mp, nrm, partials, nh);
    finalize2<<<1, 64, 0, stream>>>(partials, (float*)d_out, 1.0f / 131072.0f);
}

// Round 9
// 70.378 us; speedup vs baseline: 2.4154x; 2.4154x over previous
//
#include <hip/hip_runtime.h>
#include <math.h>

// Problem shape (fixed by harness reference)
#define B_SZ 32
#define NM   2048     // N == M == 2048
#define D_SZ 32

typedef __attribute__((ext_vector_type(8))) _Float16 h8;   // MFMA A/B frag: 8 f16 = 4 VGPRs
typedef __attribute__((ext_vector_type(4))) float f4;      // MFMA C/D frag

// ---------------------------------------------------------------------------
// Pack X (and Y) into MFMA-fragment-ready f16 layout + fused squared norms
// (verified: absmax 0.0 in rounds 2-8). Tile t = 16 consecutive rows of
// flattened [B*NM]; lane l holds row t*16+(l&15), k = {4g+j} U {16+4g+j}.
// ---------------------------------------------------------------------------
__global__ __launch_bounds__(256)
void pack_kernel(const float* __restrict__ srcX, const float* __restrict__ srcY,
                 h8* __restrict__ dstX, h8* __restrict__ dstY,
                 float* __restrict__ nrmX, float* __restrict__ nrmY)
{
    const int gid = blockIdx.x * 256 + threadIdx.x;   // one thread per (tile,lane)
    const float* src = blockIdx.y ? srcY : srcX;
    h8*          dst = blockIdx.y ? dstY : dstX;
    float*       nrm = blockIdx.y ? nrmY : nrmX;

    const int l   = gid & 63;
    const int t   = gid >> 6;
    const int row = t * 16 + (l & 15);
    const int k0  = (l >> 4) * 4;

    const float* p = src + (size_t)row * D_SZ;
    f4 v0 = *(const f4*)(p + k0);        // k = k0..k0+3
    f4 v1 = *(const f4*)(p + 16 + k0);   // k = 16+k0..16+k0+3

    h8 h;
    h[0] = (_Float16)v0[0]; h[1] = (_Float16)v0[1];
    h[2] = (_Float16)v0[2]; h[3] = (_Float16)v0[3];
    h[4] = (_Float16)v1[0]; h[5] = (_Float16)v1[1];
    h[6] = (_Float16)v1[2]; h[7] = (_Float16)v1[3];
    dst[gid] = h;

    float s = 0.f;
#pragma unroll
    for (int j = 0; j < 4; ++j) {
        s = fmaf(v0[j], v0[j], s);
        s = fmaf(v1[j], v1[j], s);
    }
    s += __shfl_xor(s, 16);
    s += __shfl_xor(s, 32);
    if (l < 16) nrm[row] = s;   // exact fp32 norms
}

// ---------------------------------------------------------------------------
// One directional pass. dir=0: rows=X, cols=Y (X_inf). dir=1: roles swapped.
// Round 9: b-MAJOR XCD grouping — each XCD owns 4 complete batches (both
// dirs, all halves, all row-blocks) = ~1.1MB working set << 4MB private L2
// (round-8 lesson: per-XCD L2 working set is the binding constraint; its
// z-major 10MB/XCD spread blew FETCH to 290MB).
// Block = 4 waves, each owning 128 rows (8 A-frags, doubles MFMA per B-byte
// vs round 6); ALL waves sweep the SAME B-tile stream; 4-deep register
// prefetch (verified round 6). MFMA C-operand seeded with -0.5*qnorm[col]:
//     min_j d2[i,j] = pnorm[i] - 2 * max_j (dot[i,j] - 0.5*qnorm[j])
// End: shfl-max over 16 col-lanes, lc==0 lanes store rows directly.
// C/D layout (m89-verified): col=lane&15, row=(lane>>4)*4+reg.
// ---------------------------------------------------------------------------
#define PASS_BODY8(BF, CV)                                                    \
    {                                                                         \
        const float ch_ = -0.5f * (CV);                                       \
        const f4 cs_ = {ch_, ch_, ch_, ch_};                                  \
        f4 q0 = __builtin_amdgcn_mfma_f32_16x16x32_f16(a0, (BF), cs_, 0,0,0); \
        f4 q1 = __builtin_amdgcn_mfma_f32_16x16x32_f16(a1, (BF), cs_, 0,0,0); \
        f4 q2 = __builtin_amdgcn_mfma_f32_16x16x32_f16(a2, (BF), cs_, 0,0,0); \
        f4 q3 = __builtin_amdgcn_mfma_f32_16x16x32_f16(a3, (BF), cs_, 0,0,0); \
        f4 q4 = __builtin_amdgcn_mfma_f32_16x16x32_f16(a4, (BF), cs_, 0,0,0); \
        f4 q5 = __builtin_amdgcn_mfma_f32_16x16x32_f16(a5, (BF), cs_, 0,0,0); \
        f4 q6 = __builtin_amdgcn_mfma_f32_16x16x32_f16(a6, (BF), cs_, 0,0,0); \
        f4 q7 = __builtin_amdgcn_mfma_f32_16x16x32_f16(a7, (BF), cs_, 0,0,0); \
        _Pragma("unroll")                                                     \
        for (int r = 0; r < 4; ++r) {                                         \
            mx0[r] = fmaxf(mx0[r], q0[r]);                                    \
            mx1[r] = fmaxf(mx1[r], q1[r]);                                    \
            mx2[r] = fmaxf(mx2[r], q2[r]);                                    \
            mx3[r] = fmaxf(mx3[r], q3[r]);                                    \
            mx4[r] = fmaxf(mx4[r], q4[r]);                                    \
            mx5[r] = fmaxf(mx5[r], q5[r]);                                    \
            mx6[r] = fmaxf(mx6[r], q6[r]);                                    \
            mx7[r] = fmaxf(mx7[r], q7[r]);                                    \
        }                                                                     \
    }

__global__ __launch_bounds__(256, 4)
void chamfer_pass(const h8* __restrict__ Xpk, const h8* __restrict__ Ypk,
                  const float* __restrict__ x2g, const float* __restrict__ y2g,
                  float* __restrict__ mp, int nh, int tph /* = 128/nh */)
{
    // XCD swizzle, b-major: nwg = 32*8*nh (%8==0 -> bijective). Logical ids
    // are contiguous per XCD; decode with b as the slowest field so one XCD
    // holds complete batches.
    const int nwg  = gridDim.x;
    const int phys = blockIdx.x;
    const int lg   = (phys & 7) * (nwg >> 3) + (phys >> 3);
    const int bpb  = nwg >> 5;          // blocks per batch = 8*nh
    const int b    = lg / bpb;
    const int inner= lg % bpb;
    const int dir  = inner / (4 * nh);
    const int rr   = inner % (4 * nh);
    const int half = rr >> 2;           // 0..nh-1
    const int xb   = rr & 3;            // 4 row-blocks of 512 rows

    const int tid = threadIdx.x;
    const int w   = tid >> 6;
    const int l   = tid & 63;
    const int lc  = l & 15;
    const int g   = l >> 4;

    const h8* Ppk = dir ? Ypk : Xpk;
    const h8* Qpk = dir ? Xpk : Ypk;
    const float* qn = dir ? x2g : y2g;

    const int row0 = xb * 512 + w * 128;                  // within batch
    const size_t pt0 = ((size_t)b * NM + row0) >> 4;      // global 16-row tile
    const h8* pa = Ppk + pt0 * 64 + l;
    h8 a0 = pa[0],   a1 = pa[64],  a2 = pa[128], a3 = pa[192];
    h8 a4 = pa[256], a5 = pa[320], a6 = pa[384], a7 = pa[448];

    const int mt0 = half * tph;
    const h8*    qb  = Qpk + ((size_t)b * (NM / 16) + mt0) * 64 + l;
    const float* qnb = qn + (size_t)b * NM + mt0 * 16 + lc;

    const float NEGINF = -3.0e38f;
    f4 mx0 = {NEGINF, NEGINF, NEGINF, NEGINF};
    f4 mx1 = mx0, mx2 = mx0, mx3 = mx0;
    f4 mx4 = mx0, mx5 = mx0, mx6 = mx0, mx7 = mx0;

    // 4-deep register prefetch pipeline (tph is a multiple of 4)
    h8 b0 = qb[0], b1 = qb[64], b2 = qb[128], b3 = qb[192];
    float c0 = qnb[0], c1 = qnb[16], c2 = qnb[32], c3 = qnb[48];

    for (int t = 0; t < tph - 4; t += 4) {
        qb += 4 * 64; qnb += 4 * 16;
        h8 n0 = qb[0], n1 = qb[64], n2 = qb[128], n3 = qb[192];
        float d0 = qnb[0], d1 = qnb[16], d2 = qnb[32], d3 = qnb[48];
        PASS_BODY8(b0, c0);
        PASS_BODY8(b1, c1);
        PASS_BODY8(b2, c2);
        PASS_BODY8(b3, c3);
        b0 = n0; b1 = n1; b2 = n2; b3 = n3;
        c0 = d0; c1 = d1; c2 = d2; c3 = d3;
    }
    PASS_BODY8(b0, c0);      // tail batch
    PASS_BODY8(b1, c1);
    PASS_BODY8(b2, c2);
    PASS_BODY8(b3, c3);

    // reduce max across the 16 column-lanes
#pragma unroll
    for (int m = 1; m <= 8; m <<= 1) {
#pragma unroll
        for (int r = 0; r < 4; ++r) {
            mx0[r] = fmaxf(mx0[r], __shfl_xor(mx0[r], m));
            mx1[r] = fmaxf(mx1[r], __shfl_xor(mx1[r], m));
            mx2[r] = fmaxf(mx2[r], __shfl_xor(mx2[r], m));
            mx3[r] = fmaxf(mx3[r], __shfl_xor(mx3[r], m));
            mx4[r] = fmaxf(mx4[r], __shfl_xor(mx4[r], m));
            mx5[r] = fmaxf(mx5[r], __shfl_xor(mx5[r], m));
            mx6[r] = fmaxf(mx6[r], __shfl_xor(mx6[r], m));
            mx7[r] = fmaxf(mx7[r], __shfl_xor(mx7[r], m));
        }
    }
    if (lc == 0) {   // 4 lanes per wave; rows row0 + i*16 + g*4 .. +3
        float* out = mp + ((size_t)(dir * nh + half) * B_SZ + b) * NM
                        + row0 + (g << 2);
        *(f4*)(out)       = mx0;
        *(f4*)(out +  16) = mx1;
        *(f4*)(out +  32) = mx2;
        *(f4*)(out +  48) = mx3;
        *(f4*)(out +  64) = mx4;
        *(f4*)(out +  80) = mx5;
        *(f4*)(out +  96) = mx6;
        *(f4*)(out + 112) = mx7;
    }
}

// ---------------------------------------------------------------------------
// Finalize: d2 = nrm - 2*max(all nh halves), clamp, sqrt, deterministic sum.
// Exactly 32768 f4 elements -> grid 128 x 256, one f4 per thread.
// (verified absmax 0.0 in round 8)
// ---------------------------------------------------------------------------
__global__ __launch_bounds__(256)
void finalize1(const float* __restrict__ mp, const float* __restrict__ nrm,
               float* __restrict__ partials, int nh)
{
    const int i   = blockIdx.x * 256 + threadIdx.x;   // f4 index in [0, 32768)
    const int dir = i >> 14;
    const int r4  = i & 16383;
    const f4* n4 = (const f4*)(nrm + dir * 65536);
    const f4* mb = (const f4*)mp + (size_t)dir * nh * 16384;
    f4 pm = mb[r4];
    for (int h = 1; h < nh; ++h) {
        f4 v = mb[(size_t)h * 16384 + r4];
#pragma unroll
        for (int r = 0; r < 4; ++r) pm[r] = fmaxf(pm[r], v[r]);
    }
    f4 nv = n4[r4];
    float s = 0.f;
#pragma unroll
    for (int r = 0; r < 4; ++r) {
        float d2 = fmaf(-2.f, pm[r], nv[r]);
        s += sqrtf(fmaxf(d2, 0.f));
    }
    __shared__ float wsum[4];
#pragma unroll
    for (int o = 32; o > 0; o >>= 1) s += __shfl_down(s, o, 64);
    if ((threadIdx.x & 63) == 0) wsum[threadIdx.x >> 6] = s;
    __syncthreads();
    if (threadIdx.x == 0)
        partials[blockIdx.x] = wsum[0] + wsum[1] + wsum[2] + wsum[3];
}

__global__ __launch_bounds__(64)
void finalize2(const float* __restrict__ partials, float* __restrict__ out, float scale)
{
    float s = partials[threadIdx.x] + partials[threadIdx.x + 64];
#pragma unroll
    for (int o = 32; o > 0; o >>= 1) s += __shfl_down(s, o, 64);
    if (threadIdx.x == 0) out[0] = s * scale;
}

extern "C" void kernel_launch(void* const* d_in, const int* in_sizes, int n_in,
                              void* d_out, int out_size, void* d_ws, size_t ws_size,
                              hipStream_t stream) {
    const float* X = (const float*)d_in[0];
    const float* Y = (const float*)d_in[1];

    // ws: mp nh*131072 f + partials 128 f + nrm 131072 f + packed 8.39 MB
    const int nh  = (ws_size >= 10100000u) ? 2 : 1;
    const int tph = 128 / nh;

    float* ws       = (float*)d_ws;
    float* mp       = ws;                              // nh*2*32*2048 floats
    float* partials = mp + (size_t)nh * 131072;        // 128 floats
    float* nrm      = partials + 128;                  // 131072 floats (x2 then y2)
    h8*    Xpk      = (h8*)(nrm + 131072);             // 262144 h8 (4.19 MB)
    h8*    Ypk      = Xpk + 262144;                    // 262144 h8 (4.19 MB)

    dim3 pgrid(1024, 2);
    pack_kernel<<<pgrid, 256, 0, stream>>>(X, Y, Xpk, Ypk, nrm, nrm + 65536);

    // 1D grid: 4 row-blocks x 32 batches x 2 dir x nh halves, b-major
    // XCD-swizzled inside (512 blocks at nh=2 = 2 blocks/CU).
    chamfer_pass<<<4 * B_SZ * 2 * nh, 256, 0, stream>>>(Xpk, Ypk, nrm, nrm + 65536,
                                                        mp, nh, tph);

    finalize1<<<128, 256, 0, stream>>>(mp, nrm, partials, nh);
    finalize2<<<1, 64, 0, stream>>>(partials, (float*)d_out, 1.0f / 131072.0f);
}

// Round 10
// 40.582 us; speedup vs baseline: 4.1888x; 1.7342x over previous
//
#include <hip/hip_runtime.h>
#include <math.h>

// Problem shape (fixed by harness reference)
#define B_SZ 32
#define NM   2048     // N == M == 2048
#define D_SZ 32

typedef __attribute__((ext_vector_type(8))) _Float16 h8;   // MFMA A/B frag: 8 f16 = 4 VGPRs
typedef __attribute__((ext_vector_type(4))) float f4;      // MFMA C/D frag

// ---------------------------------------------------------------------------
// Pack X (and Y) into MFMA-fragment-ready f16 layout + fused squared norms
// (verified: absmax 0.0 in rounds 2-9). Tile t = 16 consecutive rows of
// flattened [B*NM]; lane l holds row t*16+(l&15), k = {4g+j} U {16+4g+j}.
// Round 10: also emits hnrm = -0.5*nrm (scalar) so the main loop's MFMA
// C-seed needs no multiply.
// ---------------------------------------------------------------------------
__global__ __launch_bounds__(256)
void pack_kernel(const float* __restrict__ srcX, const float* __restrict__ srcY,
                 h8* __restrict__ dstX, h8* __restrict__ dstY,
                 float* __restrict__ nrmX, float* __restrict__ nrmY,
                 float* __restrict__ hnX, float* __restrict__ hnY)
{
    const int gid = blockIdx.x * 256 + threadIdx.x;   // one thread per (tile,lane)
    const float* src = blockIdx.y ? srcY : srcX;
    h8*          dst = blockIdx.y ? dstY : dstX;
    float*       nrm = blockIdx.y ? nrmY : nrmX;
    float*       hn  = blockIdx.y ? hnY  : hnX;

    const int l   = gid & 63;
    const int t   = gid >> 6;
    const int row = t * 16 + (l & 15);
    const int k0  = (l >> 4) * 4;

    const float* p = src + (size_t)row * D_SZ;
    f4 v0 = *(const f4*)(p + k0);        // k = k0..k0+3
    f4 v1 = *(const f4*)(p + 16 + k0);   // k = 16+k0..16+k0+3

    h8 h;
    h[0] = (_Float16)v0[0]; h[1] = (_Float16)v0[1];
    h[2] = (_Float16)v0[2]; h[3] = (_Float16)v0[3];
    h[4] = (_Float16)v1[0]; h[5] = (_Float16)v1[1];
    h[6] = (_Float16)v1[2]; h[7] = (_Float16)v1[3];
    dst[gid] = h;

    float s = 0.f;
#pragma unroll
    for (int j = 0; j < 4; ++j) {
        s = fmaf(v0[j], v0[j], s);
        s = fmaf(v1[j], v1[j], s);
    }
    s += __shfl_xor(s, 16);
    s += __shfl_xor(s, 32);
    if (l < 16) {
        nrm[row] = s;            // exact fp32 norms (finalize)
        hn[row]  = -0.5f * s;    // pre-negated half norm (MFMA C-seed)
    }
}

// ---------------------------------------------------------------------------
// One directional pass. dir=0: rows=X, cols=Y (X_inf). dir=1: roles swapped.
// Structure = round 6 (verified 36.6us, VGPR 32, no spill): block = 4 waves,
// each owning 64 rows (4 A-frags); ALL waves sweep the SAME B-tile stream;
// 4-deep register prefetch. Round 10 grafts:
//  (a) b-MAJOR XCD grouping — each XCD owns 4 complete batches (~1.2MB
//      working set << 4MB private L2; round-9 idea minus its spill).
//  (b) tile-PAIR max3 epilogue — fmax(mx, fmax(qa,qb)) -> v_max3_f32,
//      halving the dominant epilogue VALU (round-7's good half; C stays a
//      scalar splat from the pre-negated hnrm, no C-operand memory load).
//     min_j d2[i,j] = pnorm[i] - 2 * max_j (dot[i,j] - 0.5*qnorm[j])
// End: shfl-max over 16 col-lanes, lc==0 lanes store rows directly.
// C/D layout (m89-verified): col=lane&15, row=(lane>>4)*4+reg.
// ---------------------------------------------------------------------------
#define PASS2(BA, CA, BB, CB)                                                  \
    {                                                                          \
        const f4 csa_ = {(CA), (CA), (CA), (CA)};                              \
        const f4 csb_ = {(CB), (CB), (CB), (CB)};                              \
        f4 qa0 = __builtin_amdgcn_mfma_f32_16x16x32_f16(a0, (BA), csa_, 0,0,0);\
        f4 qb0 = __builtin_amdgcn_mfma_f32_16x16x32_f16(a0, (BB), csb_, 0,0,0);\
        f4 qa1 = __builtin_amdgcn_mfma_f32_16x16x32_f16(a1, (BA), csa_, 0,0,0);\
        f4 qb1 = __builtin_amdgcn_mfma_f32_16x16x32_f16(a1, (BB), csb_, 0,0,0);\
        f4 qa2 = __builtin_amdgcn_mfma_f32_16x16x32_f16(a2, (BA), csa_, 0,0,0);\
        f4 qb2 = __builtin_amdgcn_mfma_f32_16x16x32_f16(a2, (BB), csb_, 0,0,0);\
        f4 qa3 = __builtin_amdgcn_mfma_f32_16x16x32_f16(a3, (BA), csa_, 0,0,0);\
        f4 qb3 = __builtin_amdgcn_mfma_f32_16x16x32_f16(a3, (BB), csb_, 0,0,0);\
        _Pragma("unroll")                                                      \
        for (int r = 0; r < 4; ++r) {                                          \
            mx0[r] = fmaxf(mx0[r], fmaxf(qa0[r], qb0[r]));                     \
            mx1[r] = fmaxf(mx1[r], fmaxf(qa1[r], qb1[r]));                     \
            mx2[r] = fmaxf(mx2[r], fmaxf(qa2[r], qb2[r]));                     \
            mx3[r] = fmaxf(mx3[r], fmaxf(qa3[r], qb3[r]));                     \
        }                                                                      \
    }

__global__ __launch_bounds__(256, 4)
void chamfer_pass(const h8* __restrict__ Xpk, const h8* __restrict__ Ypk,
                  const float* __restrict__ hnX, const float* __restrict__ hnY,
                  float* __restrict__ mp, int nh, int tph /* = 128/nh */)
{
    // XCD swizzle, b-major (nwg = 8*32*2*nh, %8==0 -> bijective): each XCD
    // gets a contiguous logical chunk = complete batches.
    const int nwg  = gridDim.x;
    const int phys = blockIdx.x;
    const int lg   = (phys & 7) * (nwg >> 3) + (phys >> 3);
    const int bpb  = nwg >> 5;          // blocks per batch = 8*2*nh/... = 16*nh
    const int b    = lg / bpb;
    const int inner= lg % bpb;
    const int dir  = inner / (8 * nh);
    const int rr   = inner % (8 * nh);
    const int half = rr >> 3;           // 0..nh-1
    const int xb   = rr & 7;            // 8 row-blocks of 256 rows

    const int tid = threadIdx.x;
    const int w   = tid >> 6;
    const int l   = tid & 63;
    const int lc  = l & 15;
    const int g   = l >> 4;

    const h8* Ppk = dir ? Ypk : Xpk;
    const h8* Qpk = dir ? Xpk : Ypk;
    const float* qn = dir ? hnX : hnY;

    const int row0 = xb * 256 + w * 64;                   // within batch
    const size_t pt0 = ((size_t)b * NM + row0) >> 4;      // global 16-row tile
    const h8* pa = Ppk + pt0 * 64 + l;
    h8 a0 = pa[0], a1 = pa[64], a2 = pa[128], a3 = pa[192];

    const int mt0 = half * tph;
    const h8*    qb  = Qpk + ((size_t)b * (NM / 16) + mt0) * 64 + l;
    const float* qnb = qn + (size_t)b * NM + mt0 * 16 + lc;

    const float NEGINF = -3.0e38f;
    f4 mx0 = {NEGINF, NEGINF, NEGINF, NEGINF};
    f4 mx1 = mx0, mx2 = mx0, mx3 = mx0;

    // 4-deep register prefetch pipeline (tph is a multiple of 4)
    h8 b0 = qb[0], b1 = qb[64], b2 = qb[128], b3 = qb[192];
    float c0 = qnb[0], c1 = qnb[16], c2 = qnb[32], c3 = qnb[48];

    for (int t = 0; t < tph - 4; t += 4) {
        qb += 4 * 64; qnb += 4 * 16;
        h8 n0 = qb[0], n1 = qb[64], n2 = qb[128], n3 = qb[192];
        float d0 = qnb[0], d1 = qnb[16], d2 = qnb[32], d3 = qnb[48];
        PASS2(b0, c0, b1, c1);
        PASS2(b2, c2, b3, c3);
        b0 = n0; b1 = n1; b2 = n2; b3 = n3;
        c0 = d0; c1 = d1; c2 = d2; c3 = d3;
    }
    PASS2(b0, c0, b1, c1);   // tail batch
    PASS2(b2, c2, b3, c3);

    // reduce max across the 16 column-lanes
#pragma unroll
    for (int m = 1; m <= 8; m <<= 1) {
#pragma unroll
        for (int r = 0; r < 4; ++r) {
            mx0[r] = fmaxf(mx0[r], __shfl_xor(mx0[r], m));
            mx1[r] = fmaxf(mx1[r], __shfl_xor(mx1[r], m));
            mx2[r] = fmaxf(mx2[r], __shfl_xor(mx2[r], m));
            mx3[r] = fmaxf(mx3[r], __shfl_xor(mx3[r], m));
        }
    }
    if (lc == 0) {   // 4 lanes per wave; rows row0 + i*16 + g*4 .. +3
        float* out = mp + ((size_t)(dir * nh + half) * B_SZ + b) * NM
                        + row0 + (g << 2);
        *(f4*)(out)      = mx0;
        *(f4*)(out + 16) = mx1;
        *(f4*)(out + 32) = mx2;
        *(f4*)(out + 48) = mx3;
    }
}

// ---------------------------------------------------------------------------
// Finalize: d2 = nrm - 2*max(all nh halves), clamp, sqrt, deterministic sum.
// Exactly 32768 f4 elements -> grid 128 x 256, one f4 per thread.
// (verified absmax 0.0 rounds 8-9)
// ---------------------------------------------------------------------------
__global__ __launch_bounds__(256)
void finalize1(const float* __restrict__ mp, const float* __restrict__ nrm,
               float* __restrict__ partials, int nh)
{
    const int i   = blockIdx.x * 256 + threadIdx.x;   // f4 index in [0, 32768)
    const int dir = i >> 14;
    const int r4  = i & 16383;
    const f4* n4 = (const f4*)(nrm + dir * 65536);
    const f4* mb = (const f4*)mp + (size_t)dir * nh * 16384;
    f4 pm = mb[r4];
    for (int h = 1; h < nh; ++h) {
        f4 v = mb[(size_t)h * 16384 + r4];
#pragma unroll
        for (int r = 0; r < 4; ++r) pm[r] = fmaxf(pm[r], v[r]);
    }
    f4 nv = n4[r4];
    float s = 0.f;
#pragma unroll
    for (int r = 0; r < 4; ++r) {
        float d2 = fmaf(-2.f, pm[r], nv[r]);
        s += sqrtf(fmaxf(d2, 0.f));
    }
    __shared__ float wsum[4];
#pragma unroll
    for (int o = 32; o > 0; o >>= 1) s += __shfl_down(s, o, 64);
    if ((threadIdx.x & 63) == 0) wsum[threadIdx.x >> 6] = s;
    __syncthreads();
    if (threadIdx.x == 0)
        partials[blockIdx.x] = wsum[0] + wsum[1] + wsum[2] + wsum[3];
}

__global__ __launch_bounds__(64)
void finalize2(const float* __restrict__ partials, float* __restrict__ out, float scale)
{
    float s = partials[threadIdx.x] + partials[threadIdx.x + 64];
#pragma unroll
    for (int o = 32; o > 0; o >>= 1) s += __shfl_down(s, o, 64);
    if (threadIdx.x == 0) out[0] = s * scale;
}

extern "C" void kernel_launch(void* const* d_in, const int* in_sizes, int n_in,
                              void* d_out, int out_size, void* d_ws, size_t ws_size,
                              hipStream_t stream) {
    const float* X = (const float*)d_in[0];
    const float* Y = (const float*)d_in[1];

    // ws: mp nh*131072 f + partials 128 f + nrm 131072 f + hnrm 131072 f
    //     + packed 8.39 MB  (~10.4 MB at nh=2)
    const int nh  = (ws_size >= 11000000u) ? 2 : 1;
    const int tph = 128 / nh;

    float* ws       = (float*)d_ws;
    float* mp       = ws;                              // nh*2*32*2048 floats
    float* partials = mp + (size_t)nh * 131072;        // 128 floats
    float* nrm      = partials + 128;                  // 131072 floats (x2 then y2)
    float* hnrm     = nrm + 131072;                    // 131072 floats (pre -0.5x)
    h8*    Xpk      = (h8*)(hnrm + 131072);            // 262144 h8 (4.19 MB)
    h8*    Ypk      = Xpk + 262144;                    // 262144 h8 (4.19 MB)

    dim3 pgrid(1024, 2);
    pack_kernel<<<pgrid, 256, 0, stream>>>(X, Y, Xpk, Ypk, nrm, nrm + 65536,
                                           hnrm, hnrm + 65536);

    // 1D grid: 8 row-blocks x 32 batches x 2 dir x nh halves, b-major
    // XCD-swizzled inside (1024 blocks at nh=2 = 4 blocks/CU).
    chamfer_pass<<<8 * B_SZ * 2 * nh, 256, 0, stream>>>(Xpk, Ypk, hnrm,
                                                        hnrm + 65536, mp, nh, tph);

    finalize1<<<128, 256, 0, stream>>>(mp, nrm, partials, nh);
    finalize2<<<1, 64, 0, stream>>>(partials, (float*)d_out, 1.0f / 131072.0f);
}

// Round 11
// 36.857 us; speedup vs baseline: 4.6122x; 1.1011x over previous
//
#include <hip/hip_runtime.h>
#include <math.h>

// Problem shape (fixed by harness reference)
#define B_SZ 32
#define NM   2048     // N == M == 2048
#define D_SZ 32

typedef __attribute__((ext_vector_type(8))) _Float16 h8;   // MFMA A/B frag: 8 f16 = 4 VGPRs
typedef __attribute__((ext_vector_type(4))) float f4;      // MFMA C/D frag

// ---------------------------------------------------------------------------
// Pack X (and Y) into MFMA-fragment-ready f16 layout + fused squared norms
// (verified: absmax 0.0 in rounds 2-10). Tile t = 16 consecutive rows of
// flattened [B*NM]; lane l holds row t*16+(l&15), k = {4g+j} U {16+4g+j}.
// ---------------------------------------------------------------------------
__global__ __launch_bounds__(256)
void pack_kernel(const float* __restrict__ srcX, const float* __restrict__ srcY,
                 h8* __restrict__ dstX, h8* __restrict__ dstY,
                 float* __restrict__ nrmX, float* __restrict__ nrmY)
{
    const int gid = blockIdx.x * 256 + threadIdx.x;   // one thread per (tile,lane)
    const float* src = blockIdx.y ? srcY : srcX;
    h8*          dst = blockIdx.y ? dstY : dstX;
    float*       nrm = blockIdx.y ? nrmY : nrmX;

    const int l   = gid & 63;
    const int t   = gid >> 6;
    const int row = t * 16 + (l & 15);
    const int k0  = (l >> 4) * 4;

    const float* p = src + (size_t)row * D_SZ;
    f4 v0 = *(const f4*)(p + k0);        // k = k0..k0+3
    f4 v1 = *(const f4*)(p + 16 + k0);   // k = 16+k0..16+k0+3

    h8 h;
    h[0] = (_Float16)v0[0]; h[1] = (_Float16)v0[1];
    h[2] = (_Float16)v0[2]; h[3] = (_Float16)v0[3];
    h[4] = (_Float16)v1[0]; h[5] = (_Float16)v1[1];
    h[6] = (_Float16)v1[2]; h[7] = (_Float16)v1[3];
    dst[gid] = h;

    float s = 0.f;
#pragma unroll
    for (int j = 0; j < 4; ++j) {
        s = fmaf(v0[j], v0[j], s);
        s = fmaf(v1[j], v1[j], s);
    }
    s += __shfl_xor(s, 16);
    s += __shfl_xor(s, 32);
    if (l < 16) nrm[row] = s;   // exact fp32 norms
}

// ---------------------------------------------------------------------------
// One directional pass. dir=0: rows=X, cols=Y (X_inf). dir=1: roles swapped.
// Structure = round 6 (best verified: 36.6us total, no spill, FETCH 12.6MB):
// z-major XCD swizzle, block = 4 waves each owning 64 rows (4 A-frags), ALL
// waves sweep the SAME B-tile stream, scalar C-splat, single-fmax epilogue.
// Round 11: ONLY change = prefetch depth 4 -> 8 (halves latency-exposure
// points; each load gets ~7 tile-computes of slack) + __launch_bounds__
// (256,3) for the ~120-VGPR live set (round-9 lesson: never run at the cap).
// MFMA C-operand seeded with -0.5*qnorm[col]:
//     min_j d2[i,j] = pnorm[i] - 2 * max_j (dot[i,j] - 0.5*qnorm[j])
// End: shfl-max over 16 col-lanes, lc==0 lanes store rows directly.
// C/D layout (m89-verified): col=lane&15, row=(lane>>4)*4+reg.
// ---------------------------------------------------------------------------
#define PASS_BODY(BF, CV)                                                     \
    {                                                                         \
        const float ch_ = -0.5f * (CV);                                       \
        const f4 cs_ = {ch_, ch_, ch_, ch_};                                  \
        f4 q0 = __builtin_amdgcn_mfma_f32_16x16x32_f16(a0, (BF), cs_, 0,0,0); \
        f4 q1 = __builtin_amdgcn_mfma_f32_16x16x32_f16(a1, (BF), cs_, 0,0,0); \
        f4 q2 = __builtin_amdgcn_mfma_f32_16x16x32_f16(a2, (BF), cs_, 0,0,0); \
        f4 q3 = __builtin_amdgcn_mfma_f32_16x16x32_f16(a3, (BF), cs_, 0,0,0); \
        _Pragma("unroll")                                                     \
        for (int r = 0; r < 4; ++r) {                                         \
            mx0[r] = fmaxf(mx0[r], q0[r]);                                    \
            mx1[r] = fmaxf(mx1[r], q1[r]);                                    \
            mx2[r] = fmaxf(mx2[r], q2[r]);                                    \
            mx3[r] = fmaxf(mx3[r], q3[r]);                                    \
        }                                                                     \
    }

__global__ __launch_bounds__(256, 3)
void chamfer_pass(const h8* __restrict__ Xpk, const h8* __restrict__ Ypk,
                  const float* __restrict__ x2g, const float* __restrict__ y2g,
                  float* __restrict__ mp, int nh, int tph /* = 128/nh */)
{
    // XCD swizzle (nwg = 512 or 1024, both %8 == 0 -> bijective)
    const int nwg  = gridDim.x;
    const int phys = blockIdx.x;
    const int lg   = (phys & 7) * (nwg >> 3) + (phys >> 3);
    const int xb   = lg & 7;            // 8 row-blocks of 256
    const int rest = lg >> 3;
    const int b    = rest & 31;
    const int z    = rest >> 5;         // 0 .. 2*nh-1
    const int dir  = z / nh;
    const int half = z % nh;

    const int tid = threadIdx.x;
    const int w   = tid >> 6;
    const int l   = tid & 63;
    const int lc  = l & 15;
    const int g   = l >> 4;

    const h8* Ppk = dir ? Ypk : Xpk;
    const h8* Qpk = dir ? Xpk : Ypk;
    const float* qn = dir ? x2g : y2g;

    const int row0 = xb * 256 + w * 64;                   // within batch
    const size_t pt0 = ((size_t)b * NM + row0) >> 4;      // global 16-row tile
    const h8* pa = Ppk + pt0 * 64 + l;
    h8 a0 = pa[0], a1 = pa[64], a2 = pa[128], a3 = pa[192];

    const int mt0 = half * tph;
    const h8*    qb  = Qpk + ((size_t)b * (NM / 16) + mt0) * 64 + l;
    const float* qnb = qn + (size_t)b * NM + mt0 * 16 + lc;

    const float NEGINF = -3.0e38f;
    f4 mx0 = {NEGINF, NEGINF, NEGINF, NEGINF};
    f4 mx1 = mx0, mx2 = mx0, mx3 = mx0;

    // 8-deep register prefetch pipeline (tph = 64 or 128, multiple of 8)
    h8 b0 = qb[0],   b1 = qb[64],  b2 = qb[128], b3 = qb[192];
    h8 b4 = qb[256], b5 = qb[320], b6 = qb[384], b7 = qb[448];
    float c0 = qnb[0],  c1 = qnb[16], c2 = qnb[32], c3 = qnb[48];
    float c4 = qnb[64], c5 = qnb[80], c6 = qnb[96], c7 = qnb[112];

    for (int t = 0; t < tph - 8; t += 8) {
        qb += 8 * 64; qnb += 8 * 16;
        h8 n0 = qb[0],   n1 = qb[64],  n2 = qb[128], n3 = qb[192];
        h8 n4 = qb[256], n5 = qb[320], n6 = qb[384], n7 = qb[448];
        float d0 = qnb[0],  d1 = qnb[16], d2 = qnb[32], d3 = qnb[48];
        float d4 = qnb[64], d5 = qnb[80], d6 = qnb[96], d7 = qnb[112];
        PASS_BODY(b0, c0);
        PASS_BODY(b1, c1);
        PASS_BODY(b2, c2);
        PASS_BODY(b3, c3);
        PASS_BODY(b4, c4);
        PASS_BODY(b5, c5);
        PASS_BODY(b6, c6);
        PASS_BODY(b7, c7);
        b0 = n0; b1 = n1; b2 = n2; b3 = n3;
        b4 = n4; b5 = n5; b6 = n6; b7 = n7;
        c0 = d0; c1 = d1; c2 = d2; c3 = d3;
        c4 = d4; c5 = d5; c6 = d6; c7 = d7;
    }
    PASS_BODY(b0, c0);       // tail batch
    PASS_BODY(b1, c1);
    PASS_BODY(b2, c2);
    PASS_BODY(b3, c3);
    PASS_BODY(b4, c4);
    PASS_BODY(b5, c5);
    PASS_BODY(b6, c6);
    PASS_BODY(b7, c7);

    // reduce max across the 16 column-lanes
#pragma unroll
    for (int m = 1; m <= 8; m <<= 1) {
#pragma unroll
        for (int r = 0; r < 4; ++r) {
            mx0[r] = fmaxf(mx0[r], __shfl_xor(mx0[r], m));
            mx1[r] = fmaxf(mx1[r], __shfl_xor(mx1[r], m));
            mx2[r] = fmaxf(mx2[r], __shfl_xor(mx2[r], m));
            mx3[r] = fmaxf(mx3[r], __shfl_xor(mx3[r], m));
        }
    }
    if (lc == 0) {   // 4 lanes per wave; rows row0 + i*16 + g*4 .. +3
        float* out = mp + ((size_t)(dir * nh + half) * B_SZ + b) * NM
                        + row0 + (g << 2);
        *(f4*)(out)      = mx0;
        *(f4*)(out + 16) = mx1;
        *(f4*)(out + 32) = mx2;
        *(f4*)(out + 48) = mx3;
    }
}

// ---------------------------------------------------------------------------
// Finalize: d2 = nrm - 2*max(all nh halves), clamp, sqrt, deterministic sum.
// Exactly 32768 f4 elements -> grid 128 x 256, one f4 per thread.
// (verified absmax 0.0 rounds 8-10)
// ---------------------------------------------------------------------------
__global__ __launch_bounds__(256)
void finalize1(const float* __restrict__ mp, const float* __restrict__ nrm,
               float* __restrict__ partials, int nh)
{
    const int i   = blockIdx.x * 256 + threadIdx.x;   // f4 index in [0, 32768)
    const int dir = i >> 14;
    const int r4  = i & 16383;
    const f4* n4 = (const f4*)(nrm + dir * 65536);
    const f4* mb = (const f4*)mp + (size_t)dir * nh * 16384;
    f4 pm = mb[r4];
    for (int h = 1; h < nh; ++h) {
        f4 v = mb[(size_t)h * 16384 + r4];
#pragma unroll
        for (int r = 0; r < 4; ++r) pm[r] = fmaxf(pm[r], v[r]);
    }
    f4 nv = n4[r4];
    float s = 0.f;
#pragma unroll
    for (int r = 0; r < 4; ++r) {
        float d2 = fmaf(-2.f, pm[r], nv[r]);
        s += sqrtf(fmaxf(d2, 0.f));
    }
    __shared__ float wsum[4];
#pragma unroll
    for (int o = 32; o > 0; o >>= 1) s += __shfl_down(s, o, 64);
    if ((threadIdx.x & 63) == 0) wsum[threadIdx.x >> 6] = s;
    __syncthreads();
    if (threadIdx.x == 0)
        partials[blockIdx.x] = wsum[0] + wsum[1] + wsum[2] + wsum[3];
}

__global__ __launch_bounds__(64)
void finalize2(const float* __restrict__ partials, float* __restrict__ out, float scale)
{
    float s = partials[threadIdx.x] + partials[threadIdx.x + 64];
#pragma unroll
    for (int o = 32; o > 0; o >>= 1) s += __shfl_down(s, o, 64);
    if (threadIdx.x == 0) out[0] = s * scale;
}

extern "C" void kernel_launch(void* const* d_in, const int* in_sizes, int n_in,
                              void* d_out, int out_size, void* d_ws, size_t ws_size,
                              hipStream_t stream) {
    const float* X = (const float*)d_in[0];
    const float* Y = (const float*)d_in[1];

    // ws: mp nh*131072 f + partials 128 f + nrm 131072 f + packed 8.39 MB
    const int nh  = (ws_size >= 10100000u) ? 2 : 1;
    const int tph = 128 / nh;

    float* ws       = (float*)d_ws;
    float* mp       = ws;                              // nh*2*32*2048 floats
    float* partials = mp + (size_t)nh * 131072;        // 128 floats
    float* nrm      = partials + 128;                  // 131072 floats (x2 then y2)
    h8*    Xpk      = (h8*)(nrm + 131072);             // 262144 h8 (4.19 MB)
    h8*    Ypk      = Xpk + 262144;                    // 262144 h8 (4.19 MB)

    dim3 pgrid(1024, 2);
    pack_kernel<<<pgrid, 256, 0, stream>>>(X, Y, Xpk, Ypk, nrm, nrm + 65536);

    // 1D grid: 8 row-blocks x 32 batches x (2*nh) passes, XCD-swizzled inside
    chamfer_pass<<<8 * B_SZ * 2 * nh, 256, 0, stream>>>(Xpk, Ypk, nrm, nrm + 65536,
                                                        mp, nh, tph);

    finalize1<<<128, 256, 0, stream>>>(mp, nrm, partials, nh);
    finalize2<<<1, 64, 0, stream>>>(partials, (float*)d_out, 1.0f / 131072.0f);
}

// Round 12
// 36.812 us; speedup vs baseline: 4.6178x; 1.0012x over previous
//
#include <hip/hip_runtime.h>
#include <math.h>

// Problem shape (fixed by harness reference)
#define B_SZ 32
#define NM   2048     // N == M == 2048
#define D_SZ 32

typedef __attribute__((ext_vector_type(8))) _Float16 h8;   // MFMA A/B frag: 8 f16 = 4 VGPRs
typedef __attribute__((ext_vector_type(4))) float f4;      // MFMA C/D frag

// ---------------------------------------------------------------------------
// Pack X (and Y) into MFMA-fragment-ready f16 layout + fused squared norms
// (verified: absmax 0.0 in rounds 2-11). Tile t = 16 consecutive rows of
// flattened [B*NM]; lane l holds row t*16+(l&15), k = {4g+j} U {16+4g+j}.
// Round 12: norms additionally written TRANSPOSED and pre-negated-halved:
//   hnT[batch][tb][lc][j] = -0.5*nrm[col=(tb*4+j)*16+lc]
// so the main loop fetches 4 tiles' C-seeds with ONE dwordx4 (TA-issue cut).
// ---------------------------------------------------------------------------
__global__ __launch_bounds__(256)
void pack_kernel(const float* __restrict__ srcX, const float* __restrict__ srcY,
                 h8* __restrict__ dstX, h8* __restrict__ dstY,
                 float* __restrict__ nrmX, float* __restrict__ nrmY,
                 float* __restrict__ hnTX, float* __restrict__ hnTY)
{
    const int gid = blockIdx.x * 256 + threadIdx.x;   // one thread per (tile,lane)
    const float* src = blockIdx.y ? srcY : srcX;
    h8*          dst = blockIdx.y ? dstY : dstX;
    float*       nrm = blockIdx.y ? nrmY : nrmX;
    float*       hnT = blockIdx.y ? hnTY : hnTX;

    const int l   = gid & 63;
    const int t   = gid >> 6;
    const int row = t * 16 + (l & 15);
    const int k0  = (l >> 4) * 4;

    const float* p = src + (size_t)row * D_SZ;
    f4 v0 = *(const f4*)(p + k0);        // k = k0..k0+3
    f4 v1 = *(const f4*)(p + 16 + k0);   // k = 16+k0..16+k0+3

    h8 h;
    h[0] = (_Float16)v0[0]; h[1] = (_Float16)v0[1];
    h[2] = (_Float16)v0[2]; h[3] = (_Float16)v0[3];
    h[4] = (_Float16)v1[0]; h[5] = (_Float16)v1[1];
    h[6] = (_Float16)v1[2]; h[7] = (_Float16)v1[3];
    dst[gid] = h;

    float s = 0.f;
#pragma unroll
    for (int j = 0; j < 4; ++j) {
        s = fmaf(v0[j], v0[j], s);
        s = fmaf(v1[j], v1[j], s);
    }
    s += __shfl_xor(s, 16);
    s += __shfl_xor(s, 32);
    if (l < 16) {
        nrm[row] = s;                                 // exact fp32 norms
        const int gb = row >> 11;                     // batch
        const int r  = row & 2047;                    // col within batch
        // tb = r>>6, lc = r&15, j = (r>>4)&3
        hnT[gb * 2048 + (r >> 6) * 64 + (r & 15) * 4 + ((r >> 4) & 3)]
            = -0.5f * s;
    }
}

// ---------------------------------------------------------------------------
// One directional pass. dir=0: rows=X, cols=Y (X_inf). dir=1: roles swapped.
// Round 12 = R6 structure with HALVED vmem-instruction count (TA-issue fix):
//  - wave owns 128 rows (8 A-frags; R9 semantics — correctness-proven) so
//    each B-load feeds 8 MFMAs instead of 4;
//  - C-seeds batch-loaded as dwordx4 from hnT (1 vmem per 4 tiles, no mul);
//  - __launch_bounds__(256,2): 256-VGPR cap so the ~115-reg live set cannot
//    spill (R9's failure mode was the (256,4)=128 cap);
//  - z-major XCD swizzle (verified round 5: FETCH 37->12.6 MB), ALL 4 waves
//    sweep the SAME B-tile stream, 4-deep register prefetch (verified R6).
//     min_j d2[i,j] = pnorm[i] - 2 * max_j (dot[i,j] - 0.5*qnorm[j])
// End: shfl-max over 16 col-lanes, lc==0 lanes store rows directly.
// C/D layout (m89-verified): col=lane&15, row=(lane>>4)*4+reg.
// ---------------------------------------------------------------------------
#define PASS_BODY8(BF, CV)                                                    \
    {                                                                         \
        const f4 cs_ = {(CV), (CV), (CV), (CV)};                              \
        f4 q0 = __builtin_amdgcn_mfma_f32_16x16x32_f16(a0, (BF), cs_, 0,0,0); \
        f4 q1 = __builtin_amdgcn_mfma_f32_16x16x32_f16(a1, (BF), cs_, 0,0,0); \
        f4 q2 = __builtin_amdgcn_mfma_f32_16x16x32_f16(a2, (BF), cs_, 0,0,0); \
        f4 q3 = __builtin_amdgcn_mfma_f32_16x16x32_f16(a3, (BF), cs_, 0,0,0); \
        f4 q4 = __builtin_amdgcn_mfma_f32_16x16x32_f16(a4, (BF), cs_, 0,0,0); \
        f4 q5 = __builtin_amdgcn_mfma_f32_16x16x32_f16(a5, (BF), cs_, 0,0,0); \
        f4 q6 = __builtin_amdgcn_mfma_f32_16x16x32_f16(a6, (BF), cs_, 0,0,0); \
        f4 q7 = __builtin_amdgcn_mfma_f32_16x16x32_f16(a7, (BF), cs_, 0,0,0); \
        _Pragma("unroll")                                                     \
        for (int r = 0; r < 4; ++r) {                                         \
            mx0[r] = fmaxf(mx0[r], q0[r]);                                    \
            mx1[r] = fmaxf(mx1[r], q1[r]);                                    \
            mx2[r] = fmaxf(mx2[r], q2[r]);                                    \
            mx3[r] = fmaxf(mx3[r], q3[r]);                                    \
            mx4[r] = fmaxf(mx4[r], q4[r]);                                    \
            mx5[r] = fmaxf(mx5[r], q5[r]);                                    \
            mx6[r] = fmaxf(mx6[r], q6[r]);                                    \
            mx7[r] = fmaxf(mx7[r], q7[r]);                                    \
        }                                                                     \
    }

__global__ __launch_bounds__(256, 2)
void chamfer_pass(const h8* __restrict__ Xpk, const h8* __restrict__ Ypk,
                  const float* __restrict__ hnTX, const float* __restrict__ hnTY,
                  float* __restrict__ mp, int nh, int tph /* = 128/nh */)
{
    // z-major XCD swizzle (nwg = 256 or 512, both %8 == 0 -> bijective)
    const int nwg  = gridDim.x;
    const int phys = blockIdx.x;
    const int lg   = (phys & 7) * (nwg >> 3) + (phys >> 3);
    const int xb   = lg & 3;            // 4 row-blocks of 512 rows
    const int rest = lg >> 2;
    const int b    = rest & 31;
    const int z    = rest >> 5;         // 0 .. 2*nh-1
    const int dir  = z / nh;
    const int half = z % nh;

    const int tid = threadIdx.x;
    const int w   = tid >> 6;
    const int l   = tid & 63;
    const int lc  = l & 15;
    const int g   = l >> 4;

    const h8* Ppk = dir ? Ypk : Xpk;
    const h8* Qpk = dir ? Xpk : Ypk;
    const float* qn = dir ? hnTX : hnTY;

    const int row0 = xb * 512 + w * 128;                  // within batch
    const size_t pt0 = ((size_t)b * NM + row0) >> 4;      // global 16-row tile
    const h8* pa = Ppk + pt0 * 64 + l;
    h8 a0 = pa[0],   a1 = pa[64],  a2 = pa[128], a3 = pa[192];
    h8 a4 = pa[256], a5 = pa[320], a6 = pa[384], a7 = pa[448];

    const int mt0 = half * tph;                           // first tile index
    const h8* qb = Qpk + ((size_t)b * (NM / 16) + mt0) * 64 + l;
    const f4* qc = (const f4*)(qn + (size_t)b * NM + (mt0 >> 2) * 64 + lc * 4);

    const float NEGINF = -3.0e38f;
    f4 mx0 = {NEGINF, NEGINF, NEGINF, NEGINF};
    f4 mx1 = mx0, mx2 = mx0, mx3 = mx0;
    f4 mx4 = mx0, mx5 = mx0, mx6 = mx0, mx7 = mx0;

    // 4-deep register prefetch pipeline (tph is a multiple of 4)
    h8 b0 = qb[0], b1 = qb[64], b2 = qb[128], b3 = qb[192];
    f4 cc = qc[0];                       // C-seeds for tiles 0..3 (this lane)

    for (int t = 0; t < tph - 4; t += 4) {
        qb += 4 * 64; qc += 16;          // 16 f4 = 64 floats per 4-tile group
        h8 n0 = qb[0], n1 = qb[64], n2 = qb[128], n3 = qb[192];
        f4 dd = qc[0];
        PASS_BODY8(b0, cc[0]);
        PASS_BODY8(b1, cc[1]);
        PASS_BODY8(b2, cc[2]);
        PASS_BODY8(b3, cc[3]);
        b0 = n0; b1 = n1; b2 = n2; b3 = n3;
        cc = dd;
    }
    PASS_BODY8(b0, cc[0]);   // tail batch
    PASS_BODY8(b1, cc[1]);
    PASS_BODY8(b2, cc[2]);
    PASS_BODY8(b3, cc[3]);

    // reduce max across the 16 column-lanes
#pragma unroll
    for (int m = 1; m <= 8; m <<= 1) {
#pragma unroll
        for (int r = 0; r < 4; ++r) {
            mx0[r] = fmaxf(mx0[r], __shfl_xor(mx0[r], m));
            mx1[r] = fmaxf(mx1[r], __shfl_xor(mx1[r], m));
            mx2[r] = fmaxf(mx2[r], __shfl_xor(mx2[r], m));
            mx3[r] = fmaxf(mx3[r], __shfl_xor(mx3[r], m));
            mx4[r] = fmaxf(mx4[r], __shfl_xor(mx4[r], m));
            mx5[r] = fmaxf(mx5[r], __shfl_xor(mx5[r], m));
            mx6[r] = fmaxf(mx6[r], __shfl_xor(mx6[r], m));
            mx7[r] = fmaxf(mx7[r], __shfl_xor(mx7[r], m));
        }
    }
    if (lc == 0) {   // 4 lanes per wave; rows row0 + i*16 + g*4 .. +3
        float* out = mp + ((size_t)(dir * nh + half) * B_SZ + b) * NM
                        + row0 + (g << 2);
        *(f4*)(out)       = mx0;
        *(f4*)(out +  16) = mx1;
        *(f4*)(out +  32) = mx2;
        *(f4*)(out +  48) = mx3;
        *(f4*)(out +  64) = mx4;
        *(f4*)(out +  80) = mx5;
        *(f4*)(out +  96) = mx6;
        *(f4*)(out + 112) = mx7;
    }
}

// ---------------------------------------------------------------------------
// Finalize: d2 = nrm - 2*max(all nh halves), clamp, sqrt, deterministic sum.
// Exactly 32768 f4 elements -> grid 128 x 256, one f4 per thread.
// (verified absmax 0.0 rounds 8-11)
// ---------------------------------------------------------------------------
__global__ __launch_bounds__(256)
void finalize1(const float* __restrict__ mp, const float* __restrict__ nrm,
               float* __restrict__ partials, int nh)
{
    const int i   = blockIdx.x * 256 + threadIdx.x;   // f4 index in [0, 32768)
    const int dir = i >> 14;
    const int r4  = i & 16383;
    const f4* n4 = (const f4*)(nrm + dir * 65536);
    const f4* mb = (const f4*)mp + (size_t)dir * nh * 16384;
    f4 pm = mb[r4];
    for (int h = 1; h < nh; ++h) {
        f4 v = mb[(size_t)h * 16384 + r4];
#pragma unroll
        for (int r = 0; r < 4; ++r) pm[r] = fmaxf(pm[r], v[r]);
    }
    f4 nv = n4[r4];
    float s = 0.f;
#pragma unroll
    for (int r = 0; r < 4; ++r) {
        float d2 = fmaf(-2.f, pm[r], nv[r]);
        s += sqrtf(fmaxf(d2, 0.f));
    }
    __shared__ float wsum[4];
#pragma unroll
    for (int o = 32; o > 0; o >>= 1) s += __shfl_down(s, o, 64);
    if ((threadIdx.x & 63) == 0) wsum[threadIdx.x >> 6] = s;
    __syncthreads();
    if (threadIdx.x == 0)
        partials[blockIdx.x] = wsum[0] + wsum[1] + wsum[2] + wsum[3];
}

__global__ __launch_bounds__(64)
void finalize2(const float* __restrict__ partials, float* __restrict__ out, float scale)
{
    float s = partials[threadIdx.x] + partials[threadIdx.x + 64];
#pragma unroll
    for (int o = 32; o > 0; o >>= 1) s += __shfl_down(s, o, 64);
    if (threadIdx.x == 0) out[0] = s * scale;
}

extern "C" void kernel_launch(void* const* d_in, const int* in_sizes, int n_in,
                              void* d_out, int out_size, void* d_ws, size_t ws_size,
                              hipStream_t stream) {
    const float* X = (const float*)d_in[0];
    const float* Y = (const float*)d_in[1];

    // ws: mp nh*131072 f + partials 128 f + nrm 131072 f + hnT 131072 f
    //     + packed 8.39 MB  (~10.4 MB at nh=2)
    const int nh  = (ws_size >= 11000000u) ? 2 : 1;
    const int tph = 128 / nh;

    float* ws       = (float*)d_ws;
    float* mp       = ws;                              // nh*2*32*2048 floats
    float* partials = mp + (size_t)nh * 131072;        // 128 floats
    float* nrm      = partials + 128;                  // 131072 floats (x2 then y2)
    float* hnT      = nrm + 131072;                    // 131072 floats (transposed -0.5x)
    h8*    Xpk      = (h8*)(hnT + 131072);             // 262144 h8 (4.19 MB)
    h8*    Ypk      = Xpk + 262144;                    // 262144 h8 (4.19 MB)

    dim3 pgrid(1024, 2);
    pack_kernel<<<pgrid, 256, 0, stream>>>(X, Y, Xpk, Ypk, nrm, nrm + 65536,
                                           hnT, hnT + 65536);

    // 1D grid: 4 row-blocks x 32 batches x (2*nh) passes, XCD-swizzled inside
    // (512 blocks at nh=2 = exactly 2 blocks/CU, single round, no tail)
    chamfer_pass<<<4 * B_SZ * 2 * nh, 256, 0, stream>>>(Xpk, Ypk, hnT,
                                                        hnT + 65536, mp, nh, tph);

    finalize1<<<128, 256, 0, stream>>>(mp, nrm, partials, nh);
    finalize2<<<1, 64, 0, stream>>>(partials, (float*)d_out, 1.0f / 131072.0f);
}